// Round 2
// baseline (87192.804 us; speedup 1.0000x reference)
//
#include <hip/hip_runtime.h>

// NeuralCDEDecoder: B=512, T=257, IN=32, H=128, BN=256, OUT=64, K_SUB=4.
// Persistent batch-parallel design: 32 workgroups x 16 batch rows, whole
// 256-interval x 4-substep x 4-stage RK4 loop inside one kernel.
// Weights pre-packed (pack_weight) into mfma_f32_16x16x32_bf16 B-fragment
// order in MODULE __device__ GLOBALS (NOT d_ws: round-1 failure was pack
// overflowing ws_size and corrupting the harness's pristine input copies,
// so call 1 passed and every later call diverged). Globals are rewritten
// every call (same work per call). fp32 state/accum, bf16 MFMA operands.

using short8   = __attribute__((ext_vector_type(8))) short;
using float4v  = __attribute__((ext_vector_type(4))) float;
using ushort4v = __attribute__((ext_vector_type(4))) unsigned short;

// Packed weights: 2,326,528 bytes total, module-static.
__device__ unsigned short g_w1p[32768];
__device__ unsigned short g_w2p[65536];
__device__ unsigned short g_w3p[1048576];
__device__ unsigned short g_mwp[8192];
__device__ unsigned short g_swp[8192];

__device__ __forceinline__ unsigned short* pack_dst(int which){
  switch (which){
    case 0:  return g_w1p;
    case 1:  return g_w2p;
    case 2:  return g_w3p;
    case 3:  return g_mwp;
    default: return g_swp;
  }
}

__device__ __forceinline__ float bf2f(unsigned short h){
  union { unsigned int u; float f; } v; v.u = ((unsigned int)h) << 16; return v.f;
}
__device__ __forceinline__ unsigned short f2bf(float f){
  union { float f; unsigned int u; } v; v.f = f;
  unsigned int u = v.u;
  return (unsigned short)((u + 0x7FFFu + ((u >> 16) & 1u)) >> 16);  // RNE
}
template<bool BF16> __device__ __forceinline__ float loadf(const void* p, long i){
  if constexpr (BF16) return bf2f(((const unsigned short*)p)[i]);
  else                return ((const float*)p)[i];
}
// t[0]=0.0 always; bytes 2..3 are high half of f32 t[0] (=0) or bf16 t[1] (!=0).
__device__ __forceinline__ bool input_is_bf16(const void* t){
  return ((const unsigned short*)t)[1] != 0;
}
__device__ __forceinline__ float tanh_f(float x){
  float e = __builtin_amdgcn_exp2f(x * 2.88539008177793f);          // e^{2x}
  return 1.f - 2.f * __builtin_amdgcn_rcpf(e + 1.f);
}
__device__ __forceinline__ float softplus_f(float x){
  if (x > 20.f) return x;
  float e = __builtin_amdgcn_exp2f(x * 1.44269504088896f);
  return __builtin_amdgcn_logf(1.f + e) * 0.693147180559945f;       // log2->ln
}

// Pack row-major [K,N] weight into fragment order:
// tile (nt,kt) -> 512 bf16 at ((nt*KT+kt)<<9); element (lane,j) = W[kt*32+(lane>>4)*8+j][nt*16+(lane&15)]
template<bool BF16>
__global__ __launch_bounds__(256)
void pack_weight(const void* __restrict__ src, int which,
                 int K, int N, const void* __restrict__ tchk){
  if (input_is_bf16(tchk) != BF16) return;
  unsigned short* dst = pack_dst(which);
  const int KT = K >> 5;
  const long total = (long)(N >> 4) * KT * 512;
  for (long e = (long)blockIdx.x * blockDim.x + threadIdx.x; e < total;
       e += (long)gridDim.x * blockDim.x){
    int  r    = (int)(e & 511);
    long tile = e >> 9;
    int  kt   = (int)(tile % KT);
    int  nt   = (int)(tile / KT);
    int  ln   = r >> 3, j = r & 7;
    int  k    = (kt << 5) + ((ln >> 4) << 3) + j;
    int  n    = (nt << 4) + (ln & 15);
    long si   = (long)k * N + n;
    dst[e] = BF16 ? ((const unsigned short*)src)[si] : f2bf(((const float*)src)[si]);
  }
}

#define STRZ 136   // z buffer row stride (128+8 bf16) -> 2-way-free LDS banks
#define STRH 264   // h buffer row stride (256+8 bf16)
#define STRV 132   // vf row stride (fp32)
#define STRD 33    // dxdt row stride (fp32)

template<bool BF16>
__global__ __launch_bounds__(512, 2)
void cde_main(const void* __restrict__ tin,  const void* __restrict__ z0in,
              const void* __restrict__ Xin,
              const void* __restrict__ b1in, const void* __restrict__ b2in,
              const void* __restrict__ b3in, const void* __restrict__ mbin,
              const void* __restrict__ sbin,
              void* __restrict__ outv)
{
  if (input_is_bf16(tin) != BF16) return;

  const unsigned short* __restrict__ w1p = g_w1p;
  const unsigned short* __restrict__ w2p = g_w2p;
  const unsigned short* __restrict__ w3p = g_w3p;
  const unsigned short* __restrict__ mwp = g_mwp;
  const unsigned short* __restrict__ swp = g_swp;

  __shared__ __align__(16) unsigned short bufZ [16 * STRZ];
  __shared__ __align__(16) unsigned short bufH1[16 * STRH];
  __shared__ __align__(16) unsigned short bufH2[16 * STRH];
  __shared__ __align__(16) float          vfs  [16 * STRV];
  __shared__ __align__(16) float          dxs  [16 * STRD];
  __shared__ __align__(16) float          biasl[4736];      // b1|b2|b3|mb|sb

  const int tid  = threadIdx.x;
  const int lane = tid & 63;
  const int wv   = tid >> 6;        // wave 0..7
  const int c16  = lane & 15;       // MFMA row(A)/col(B,D)
  const int quad = lane >> 4;       // 0..3
  const int m0   = blockIdx.x * 16; // batch-row base

  // biases -> LDS (fp32)
  for (int i = tid; i < 4736; i += 512){
    float v;
    if      (i < 256)  v = loadf<BF16>(b1in, i);
    else if (i < 512)  v = loadf<BF16>(b2in, i - 256);
    else if (i < 4608) v = loadf<BF16>(b3in, i - 512);
    else if (i < 4672) v = loadf<BF16>(mbin, i - 4608);
    else               v = loadf<BF16>(sbin, i - 4672);
    biasl[i] = v;
  }

  // per-thread z-state: thread owns (zm, zd..zd+3)
  const int zm = tid >> 5;
  const int zd = (tid & 31) << 2;
  float z[4], zacc[4];
  #pragma unroll
  for (int r = 0; r < 4; ++r) z[r] = loadf<BF16>(z0in, (long)(m0 + zm) * 128 + zd + r);
  {
    ushort4v s;
    #pragma unroll
    for (int r = 0; r < 4; ++r) s[r] = f2bf(z[r]);
    *(ushort4v*)&bufZ[zm * STRZ + zd] = s;
  }

  for (int ti = 0; ti < 256; ++ti){
    const float dt = loadf<BF16>(tin, ti + 1) - loadf<BF16>(tin, ti);
    const float hs = dt * 0.25f;                       // RK4 substep h
    {
      const int m = tid >> 5, i = tid & 31;
      float xc = loadf<BF16>(Xin, ((long)(m0 + m) * 257 + ti    ) * 32 + i);
      float xn = loadf<BF16>(Xin, ((long)(m0 + m) * 257 + ti + 1) * 32 + i);
      dxs[m * STRD + i] = (xn - xc) / dt;
    }
    __syncthreads();                                   // dxs (and initial bufZ/bias) ready
    float dd[2][4];                                    // hoisted dxdt for layer-3 epilogue
    #pragma unroll
    for (int ih = 0; ih < 2; ++ih)
      #pragma unroll
      for (int r = 0; r < 4; ++r)
        dd[ih][r] = dxs[(quad * 4 + r) * STRD + ih * 16 + c16];

    for (int sub = 0; sub < 4; ++sub){
      for (int st = 0; st < 4; ++st){
        __syncthreads();                               // [A] stage input in bufZ

        // -------- layer 1: relu(z @ W1 + b1)  K=128 N=256
        {
          short8 a[4];
          #pragma unroll
          for (int kt = 0; kt < 4; ++kt)
            a[kt] = *(const short8*)&bufZ[c16 * STRZ + kt * 32 + quad * 8];
          #pragma unroll
          for (int t2 = 0; t2 < 2; ++t2){
            const int nt = wv * 2 + t2;
            const unsigned short* wp = w1p + ((long)(nt * 4) << 9) + lane * 8;
            short8 b[4];
            #pragma unroll
            for (int kt = 0; kt < 4; ++kt) b[kt] = *(const short8*)(wp + (kt << 9));
            float bv = biasl[nt * 16 + c16];
            float4v acc = { bv, bv, bv, bv };
            #pragma unroll
            for (int kt = 0; kt < 4; ++kt)
              acc = __builtin_amdgcn_mfma_f32_16x16x32_bf16(a[kt], b[kt], acc, 0, 0, 0);
            #pragma unroll
            for (int r = 0; r < 4; ++r){
              float v = acc[r] > 0.f ? acc[r] : 0.f;
              bufH1[(quad * 4 + r) * STRH + nt * 16 + c16] = f2bf(v);
            }
          }
        }
        __syncthreads();                               // [B]

        // -------- layer 2: relu(h1 @ W2 + b2)  K=256 N=256
        {
          short8 a[8];
          #pragma unroll
          for (int kt = 0; kt < 8; ++kt)
            a[kt] = *(const short8*)&bufH1[c16 * STRH + kt * 32 + quad * 8];
          #pragma unroll
          for (int t2 = 0; t2 < 2; ++t2){
            const int nt = wv * 2 + t2;
            const unsigned short* wp = w2p + ((long)(nt * 8) << 9) + lane * 8;
            short8 b[8];
            #pragma unroll
            for (int kt = 0; kt < 8; ++kt) b[kt] = *(const short8*)(wp + (kt << 9));
            float bv = biasl[256 + nt * 16 + c16];
            float4v acc = { bv, bv, bv, bv };
            #pragma unroll
            for (int kt = 0; kt < 8; ++kt)
              acc = __builtin_amdgcn_mfma_f32_16x16x32_bf16(a[kt], b[kt], acc, 0, 0, 0);
            #pragma unroll
            for (int r = 0; r < 4; ++r){
              float v = acc[r] > 0.f ? acc[r] : 0.f;
              bufH2[(quad * 4 + r) * STRH + nt * 16 + c16] = f2bf(v);
            }
          }
        }
        __syncthreads();                               // [C]

        // -------- layer 3 + contraction: vf = tanh(h2@W3+b3) . dxdt
        // wave w owns global ntiles w*32..w*32+31 -> h = w*16..w*16+15 exclusively
        {
          short8 a[8];
          #pragma unroll
          for (int kt = 0; kt < 8; ++kt)
            a[kt] = *(const short8*)&bufH2[c16 * STRH + kt * 32 + quad * 8];

          const int ntbase = wv * 32;
          short8 bA[8], bB[8];
          {
            const unsigned short* wp = w3p + ((long)(ntbase * 8) << 9) + lane * 8;
            #pragma unroll
            for (int kt = 0; kt < 8; ++kt) bA[kt] = *(const short8*)(wp + (kt << 9));
          }
          float hacc[4];
          #pragma unroll 1
          for (int j = 0; j < 32; j += 2){
            { // prefetch tile j+1
              const unsigned short* wp = w3p + ((long)((ntbase + j + 1) * 8) << 9) + lane * 8;
              #pragma unroll
              for (int kt = 0; kt < 8; ++kt) bB[kt] = *(const short8*)(wp + (kt << 9));
            }
            { // tile j (i-half 0)
              const int nt = ntbase + j;
              float bv = biasl[512 + nt * 16 + c16];
              float4v acc = { bv, bv, bv, bv };
              #pragma unroll
              for (int kt = 0; kt < 8; ++kt)
                acc = __builtin_amdgcn_mfma_f32_16x16x32_bf16(a[kt], bA[kt], acc, 0, 0, 0);
              #pragma unroll
              for (int r = 0; r < 4; ++r)
                hacc[r] = tanh_f(acc[r]) * dd[0][r];
            }
            { // prefetch tile j+2 (clamped; duplicate load is harmless)
              const int jn = (j + 2 < 32) ? (j + 2) : 31;
              const unsigned short* wp = w3p + ((long)((ntbase + jn) * 8) << 9) + lane * 8;
              #pragma unroll
              for (int kt = 0; kt < 8; ++kt) bA[kt] = *(const short8*)(wp + (kt << 9));
            }
            { // tile j+1 (i-half 1) + 16-lane reduce + vf write
              const int nt = ntbase + j + 1;
              float bv = biasl[512 + nt * 16 + c16];
              float4v acc = { bv, bv, bv, bv };
              #pragma unroll
              for (int kt = 0; kt < 8; ++kt)
                acc = __builtin_amdgcn_mfma_f32_16x16x32_bf16(a[kt], bB[kt], acc, 0, 0, 0);
              const int hidx = (ntbase + j) >> 1;
              #pragma unroll
              for (int r = 0; r < 4; ++r){
                float s = hacc[r] + tanh_f(acc[r]) * dd[1][r];
                #pragma unroll
                for (int msk = 1; msk < 16; msk <<= 1)
                  s += __shfl_xor(s, msk, 64);
                if (c16 == r) vfs[(quad * 4 + r) * STRV + hidx] = s;
              }
            }
          }
        }
        __syncthreads();                               // [D]

        // -------- RK4 stage combine (registers) + write next stage input
        {
          float4v k = *(const float4v*)&vfs[zm * STRV + zd];
          float nin[4];
          if (st == 0){
            #pragma unroll
            for (int r = 0; r < 4; ++r){
              zacc[r] = z[r] + (hs * (1.f / 6.f)) * k[r];
              nin[r]  = z[r] + 0.5f * hs * k[r];
            }
          } else if (st == 1){
            #pragma unroll
            for (int r = 0; r < 4; ++r){
              zacc[r] += (hs * (1.f / 3.f)) * k[r];
              nin[r]   = z[r] + 0.5f * hs * k[r];
            }
          } else if (st == 2){
            #pragma unroll
            for (int r = 0; r < 4; ++r){
              zacc[r] += (hs * (1.f / 3.f)) * k[r];
              nin[r]   = z[r] + hs * k[r];
            }
          } else {
            #pragma unroll
            for (int r = 0; r < 4; ++r){
              z[r]   = zacc[r] + (hs * (1.f / 6.f)) * k[r];
              nin[r] = z[r];
            }
          }
          ushort4v s;
          #pragma unroll
          for (int r = 0; r < 4; ++r) s[r] = f2bf(nin[r]);
          *(ushort4v*)&bufZ[zm * STRZ + zd] = s;
        }
      } // st
    } // sub

    __syncthreads();                                   // bufZ holds z(t[ti+1])
    // -------- decoder: mean = z@mW+mb ; std = softplus(z@sW+sb)
    {
      short8 a[4];
      #pragma unroll
      for (int kt = 0; kt < 4; ++kt)
        a[kt] = *(const short8*)&bufZ[c16 * STRZ + kt * 32 + quad * 8];
      const int  nt    = wv & 3;
      const bool isStd = wv >= 4;
      const unsigned short* wp = (isStd ? swp : mwp) + ((long)(nt * 4) << 9) + lane * 8;
      short8 b[4];
      #pragma unroll
      for (int kt = 0; kt < 4; ++kt) b[kt] = *(const short8*)(wp + (kt << 9));
      float bv = biasl[(isStd ? 4672 : 4608) + nt * 16 + c16];
      float4v acc = { bv, bv, bv, bv };
      #pragma unroll
      for (int kt = 0; kt < 4; ++kt)
        acc = __builtin_amdgcn_mfma_f32_16x16x32_bf16(a[kt], b[kt], acc, 0, 0, 0);
      const long obase = isStd ? 8388608L : 0L;        // B*(T-1)*OUT
      #pragma unroll
      for (int r = 0; r < 4; ++r){
        float v = acc[r];
        if (isStd) v = softplus_f(v);
        long oi = obase + ((long)(m0 + quad * 4 + r) * 256 + ti) * 64 + nt * 16 + c16;
        if constexpr (BF16) ((unsigned short*)outv)[oi] = f2bf(v);
        else                ((float*)outv)[oi] = v;
      }
    }
  } // ti
}

extern "C" void kernel_launch(void* const* d_in, const int* in_sizes, int n_in,
                              void* d_out, int out_size, void* d_ws, size_t ws_size,
                              hipStream_t stream)
{
  const void* t  = d_in[0];
  const void* z0 = d_in[1];
  const void* X  = d_in[2];
  const void* W1 = d_in[3];
  const void* b1 = d_in[4];
  const void* W2 = d_in[5];
  const void* b2 = d_in[6];
  const void* W3 = d_in[7];
  const void* b3 = d_in[8];
  const void* mW = d_in[9];
  const void* mb = d_in[10];
  const void* sW = d_in[11];
  const void* sb = d_in[12];

  // Both dtype variants launched; each checks input dtype and the
  // non-matching one returns immediately (t[0]==0.0 discriminator).
  pack_weight<true ><<<256, 256, 0, stream>>>(W1, 0, 128,  256, t);
  pack_weight<true ><<<256, 256, 0, stream>>>(W2, 1, 256,  256, t);
  pack_weight<true ><<<512, 256, 0, stream>>>(W3, 2, 256, 4096, t);
  pack_weight<true ><<< 64, 256, 0, stream>>>(mW, 3, 128,   64, t);
  pack_weight<true ><<< 64, 256, 0, stream>>>(sW, 4, 128,   64, t);
  pack_weight<false><<<256, 256, 0, stream>>>(W1, 0, 128,  256, t);
  pack_weight<false><<<256, 256, 0, stream>>>(W2, 1, 256,  256, t);
  pack_weight<false><<<512, 256, 0, stream>>>(W3, 2, 256, 4096, t);
  pack_weight<false><<< 64, 256, 0, stream>>>(mW, 3, 128,   64, t);
  pack_weight<false><<< 64, 256, 0, stream>>>(sW, 4, 128,   64, t);

  cde_main<true ><<<32, 512, 0, stream>>>(t, z0, X, b1, b2, b3, mb, sb, d_out);
  cde_main<false><<<32, 512, 0, stream>>>(t, z0, X, b1, b2, b3, mb, sb, d_out);
  (void)in_sizes; (void)n_in; (void)out_size; (void)d_ws; (void)ws_size;
}